// Round 4
// baseline (2907.449 us; speedup 1.0000x reference)
//
#include <hip/hip_runtime.h>
#include <hip/hip_bf16.h>

// T=2048, B=64, IN=512, H=256, L=3, OUT=2.
// KEY INSIGHT 1: reference output = h[:, -1, :] = BATCH ELEMENT 63 only, and the
//   RNN recurrence is batch-diagonal -> compute a single-sequence 3-layer RNN (64x cut).
// KEY INSIGHT 2: layer l step t only needs layer l-1 outputs up to t -> run all
//   three scans CONCURRENTLY as a 6-block producer/consumer pipeline
//   (scan0 -> ih1 -> scan1 -> ih2 -> scan2 -> out), chunk-synchronized through
//   agent-scope flags. ~3x over sequential scans.
// Critical-path floor: 2048 steps x 512 cy (65536 f32 MACs / 128 FMA-lanes/CU/cy).
// R4 fix: pre-chunk values were held in a runtime-indexed private array (pc[r])
//   -> scratch spill on the critical path (rule #20). Now staged in LDS.

#define T_STEPS 2048
#define B_SZ    64
#define IN_F    512
#define H_SZ    256
#define OUT_F   2
#define CHUNK   16
#define NCHUNK  (T_STEPS / CHUNK)

__device__ __forceinline__ float fast_tanh(float x) {
    // tanh(x) = 1 - 2/(e^{2x}+1); v_exp-based, ~1e-6 rel err, saturates correctly.
    float e = __expf(2.f * x);
    return 1.f - 2.f / (e + 1.f);
}

// ---- cross-block chunk synchronization (agent scope, cross-XCD safe) --------
// Release: __threadfence (agent-scope fence) then release flag store.
// Acquire: thread 0 acquire-load (invalidates this CU's L1), then __syncthreads
// orders the whole block's subsequent reads. One block = one CU.
__device__ __forceinline__ void wait_ge(int* flag, int target) {
    if (threadIdx.x == 0) {
        while (__hip_atomic_load(flag, __ATOMIC_ACQUIRE, __HIP_MEMORY_SCOPE_AGENT) < target)
            __builtin_amdgcn_s_sleep(1);
    }
    __syncthreads();
}

__device__ __forceinline__ void post_flag(int* flag, int val) {
    __threadfence();   // each thread's global writes visible at agent scope
    __syncthreads();   // all threads fenced before the release store
    if (threadIdx.x == 0)
        __hip_atomic_store(flag, val, __ATOMIC_RELEASE, __HIP_MEMORY_SCOPE_AGENT);
}

// ---------------------------------------------------------------------------
// Recurrent scan stage: h_t = tanh(pre_t + W_hh h_{t-1}). 512 threads.
// Thread t: row j=t>>1, half p=t&1 holds W_hh[j][p*128..] in 128 VGPRs
// (all accesses compile-time indexed -> stays in registers).
// h double-buffered in LDS -> ONE barrier per step. LDS h reads are 2 distinct
// float4 addrs/wave = free broadcast (m136). Half-row partials via shfl_xor(1).
// pre chunk staged in LDS ps[][] (16 KB) -> per-step ps[r][j] is a broadcast
// LDS read, no scratch.
// ---------------------------------------------------------------------------
__device__ void scan_stage(const float* __restrict__ pre, const float* __restrict__ Whh,
                           float* __restrict__ Hout, int* wait_f, int* post_f)
{
    __shared__ __align__(16) float h2[2][H_SZ];          // 2 KB
    __shared__ __align__(16) float ps[CHUNK][H_SZ];      // 16 KB
    const int tid = threadIdx.x;
    const int j = tid >> 1;
    const int p = tid & 1;

    float w[128];
    {
        const float4* wrow = (const float4*)(Whh + j * H_SZ + p * 128);
        #pragma unroll
        for (int i = 0; i < 32; ++i) {
            float4 v = wrow[i];
            w[4*i+0] = v.x; w[4*i+1] = v.y; w[4*i+2] = v.z; w[4*i+3] = v.w;
        }
    }
    if (tid < H_SZ) h2[0][tid] = 0.f;
    __syncthreads();

    int buf = 0;
    for (int c = 0; c < NCHUNK; ++c) {
        if (wait_f) wait_ge(wait_f, c + 1);

        // stage this chunk's 16x256 pre block into LDS, coalesced float4 (16 KB)
        {
            const float4* src = (const float4*)(pre + (size_t)c * CHUNK * H_SZ);
            float4* dst = (float4*)&ps[0][0];
            dst[tid]       = src[tid];
            dst[tid + 512] = src[tid + 512];
        }
        __syncthreads();

        #pragma unroll 1
        for (int r = 0; r < CHUNK; ++r) {
            const float4* hv4 = (const float4*)(h2[buf] + p * 128);
            float a0 = 0.f, a1 = 0.f, a2 = 0.f, a3 = 0.f;
            #pragma unroll
            for (int i = 0; i < 32; ++i) {
                float4 hv = hv4[i];
                a0 = fmaf(w[4*i+0], hv.x, a0);
                a1 = fmaf(w[4*i+1], hv.y, a1);
                a2 = fmaf(w[4*i+2], hv.z, a2);
                a3 = fmaf(w[4*i+3], hv.w, a3);
            }
            float acc = (a0 + a1) + (a2 + a3);
            acc += __shfl_xor(acc, 1);               // combine half-row partials
            float hn = fast_tanh(ps[r][j] + acc);    // both lanes (no divergence)
            if (p == 0) {
                h2[buf ^ 1][j] = hn;                 // write OTHER buffer
                Hout[(size_t)(c * CHUNK + r) * H_SZ + j] = hn;
            }
            __syncthreads();                         // single barrier per step
            buf ^= 1;
        }
        if (post_f) post_flag(post_f, c + 1);
    }
}

// ---------------------------------------------------------------------------
// Streaming input-projection stage: PRE[t][j] = b1[j]+b2[j] + W_ih[j,:] . Hin[t,:]
// Same register/thread layout as scan; consumes H chunks, produces PRE chunks.
// ---------------------------------------------------------------------------
__device__ void ih_stage(const float* __restrict__ Hin, const float* __restrict__ Wih,
                         const float* __restrict__ b1, const float* __restrict__ b2,
                         float* __restrict__ PREout, int* wait_f, int* post_f)
{
    __shared__ __align__(16) float xs[CHUNK][H_SZ];   // 16 KB
    const int tid = threadIdx.x;
    const int j = tid >> 1;
    const int p = tid & 1;

    float w[128];
    {
        const float4* wrow = (const float4*)(Wih + j * H_SZ + p * 128);
        #pragma unroll
        for (int i = 0; i < 32; ++i) {
            float4 v = wrow[i];
            w[4*i+0] = v.x; w[4*i+1] = v.y; w[4*i+2] = v.z; w[4*i+3] = v.w;
        }
    }
    const float bb = b1[j] + b2[j];

    for (int c = 0; c < NCHUNK; ++c) {
        wait_ge(wait_f, c + 1);
        // stage the 16x256 h chunk into LDS, coalesced float4
        {
            const float4* src = (const float4*)(Hin + (size_t)c * CHUNK * H_SZ);
            float4* dst = (float4*)&xs[0][0];
            dst[tid]       = src[tid];
            dst[tid + 512] = src[tid + 512];
        }
        __syncthreads();

        #pragma unroll 1
        for (int r = 0; r < CHUNK; ++r) {
            const float4* hv4 = (const float4*)(xs[r] + p * 128);
            float a0 = 0.f, a1 = 0.f, a2 = 0.f, a3 = 0.f;
            #pragma unroll
            for (int i = 0; i < 32; ++i) {
                float4 hv = hv4[i];
                a0 = fmaf(w[4*i+0], hv.x, a0);
                a1 = fmaf(w[4*i+1], hv.y, a1);
                a2 = fmaf(w[4*i+2], hv.z, a2);
                a3 = fmaf(w[4*i+3], hv.w, a3);
            }
            float acc = (a0 + a1) + (a2 + a3);
            acc += __shfl_xor(acc, 1);
            if (p == 0)
                PREout[(size_t)(c * CHUNK + r) * H_SZ + j] = acc + bb;
        }
        post_flag(post_f, c + 1);   // fence+barrier also protects xs reuse
    }
}

// ---------------------------------------------------------------------------
// Output-projection stage: out[t][o] = b_out[o] + w_out[o,:] . H2[t,:].
// Wave w handles timesteps 2w, 2w+1 of each chunk (trivial work, pipeline shadow).
// ---------------------------------------------------------------------------
__device__ void out_stage(const float* __restrict__ Hs, const float* __restrict__ Wout,
                          const float* __restrict__ bout, float* __restrict__ out,
                          int* wait_f)
{
    const int tid = threadIdx.x;
    const int wv = tid >> 6;     // wave 0..7
    const int l  = tid & 63;

    float w0[4], w1[4];
    #pragma unroll
    for (int i = 0; i < 4; ++i) {
        w0[i] = Wout[l + 64 * i];
        w1[i] = Wout[H_SZ + l + 64 * i];
    }
    const float b0 = bout[0], b1 = bout[1];

    for (int c = 0; c < NCHUNK; ++c) {
        wait_ge(wait_f, c + 1);
        #pragma unroll
        for (int s = 0; s < 2; ++s) {
            const int t = c * CHUNK + wv * 2 + s;
            const float* hrow = Hs + (size_t)t * H_SZ;
            float a0 = 0.f, a1 = 0.f;
            #pragma unroll
            for (int i = 0; i < 4; ++i) {
                float hv = hrow[l + 64 * i];
                a0 = fmaf(hv, w0[i], a0);
                a1 = fmaf(hv, w1[i], a1);
            }
            #pragma unroll
            for (int sh = 32; sh; sh >>= 1) {
                a0 += __shfl_xor(a0, sh);
                a1 += __shfl_xor(a1, sh);
            }
            if (l == 0) {
                out[t * OUT_F + 0] = a0 + b0;
                out[t * OUT_F + 1] = a1 + b1;
            }
        }
    }
}

// ---------------------------------------------------------------------------
// 6-block pipeline (all co-resident: 6 blocks << 256 CUs).
// flags: 0=H0, 1=PRE1, 2=H1, 3=PRE2, 4=H2 chunk progress.
// ---------------------------------------------------------------------------
__global__ __launch_bounds__(512, 1)
void pipeline_kernel(const float* __restrict__ PRE0,
                     const float* __restrict__ w_hh0, const float* __restrict__ w_hh1,
                     const float* __restrict__ w_hh2,
                     const float* __restrict__ w_ih1, const float* __restrict__ w_ih2,
                     const float* __restrict__ b_ih1, const float* __restrict__ b_hh1,
                     const float* __restrict__ b_ih2, const float* __restrict__ b_hh2,
                     const float* __restrict__ w_out, const float* __restrict__ b_out,
                     float* __restrict__ H0, float* __restrict__ H1, float* __restrict__ H2,
                     float* __restrict__ PRE1, float* __restrict__ PRE2,
                     float* __restrict__ out, int* __restrict__ flags)
{
    switch (blockIdx.x) {
    case 0: scan_stage(PRE0, w_hh0, H0, nullptr,   flags + 0); break;
    case 1: ih_stage(H0, w_ih1, b_ih1, b_hh1, PRE1, flags + 0, flags + 1); break;
    case 2: scan_stage(PRE1, w_hh1, H1, flags + 1, flags + 2); break;
    case 3: ih_stage(H1, w_ih2, b_ih2, b_hh2, PRE2, flags + 2, flags + 3); break;
    case 4: scan_stage(PRE2, w_hh2, H2, flags + 3, flags + 4); break;
    case 5: out_stage(H2, w_out, b_out, out, flags + 4); break;
    }
}

// ---------------------------------------------------------------------------
// Layer-0 pre-GEMM (batch 63 only), fully parallel. 512 threads, 8 t per block,
// same half-row j/p layout as the scan stages (~2048 FMA/thread).
// ---------------------------------------------------------------------------
__global__ __launch_bounds__(512)
void pre_gemm_kernel(const float* __restrict__ in,
                     const float* __restrict__ W,
                     const float* __restrict__ b1, const float* __restrict__ b2,
                     float* __restrict__ pre)
{
    __shared__ __align__(16) float xs[8][IN_F];   // 16 KB
    const int tid = threadIdx.x;
    const int j = tid >> 1;
    const int p = tid & 1;
    const long t0 = (long)blockIdx.x * 8;

    // stage 8 input rows (batch 63) into LDS, coalesced float4 (128 f4/row)
    for (int idx = tid; idx < 8 * (IN_F / 4); idx += 512) {
        const int r = idx >> 7;
        const int q = idx & 127;
        const float4* srow = (const float4*)(in + (t0 + r) * ((long)B_SZ * IN_F)
                                                + (long)(B_SZ - 1) * IN_F);
        ((float4*)xs[r])[q] = srow[q];
    }
    __syncthreads();

    float acc[8] = {0.f, 0.f, 0.f, 0.f, 0.f, 0.f, 0.f, 0.f};
    const float4* wr = (const float4*)(W + (long)j * IN_F + p * (IN_F / 2));
    #pragma unroll 2
    for (int q = 0; q < IN_F / 8; ++q) {          // 64 float4 = half row (256 f)
        float4 wv = wr[q];
        #pragma unroll
        for (int r = 0; r < 8; ++r) {
            float4 xv = ((const float4*)(xs[r] + p * (IN_F / 2)))[q];
            acc[r] = fmaf(wv.x, xv.x, acc[r]);
            acc[r] = fmaf(wv.y, xv.y, acc[r]);
            acc[r] = fmaf(wv.z, xv.z, acc[r]);
            acc[r] = fmaf(wv.w, xv.w, acc[r]);
        }
    }
    const float bb = b1[j] + b2[j];
    #pragma unroll
    for (int r = 0; r < 8; ++r) {
        float v = acc[r] + __shfl_xor(acc[r], 1); // combine half-row partials
        if (p == 0)
            pre[(t0 + r) * H_SZ + j] = v + bb;
    }
}

// ---------------------------------------------------------------------------
extern "C" void kernel_launch(void* const* d_in, const int* in_sizes, int n_in,
                              void* d_out, int out_size, void* d_ws, size_t ws_size,
                              hipStream_t stream)
{
    const float* x     = (const float*)d_in[0];
    const float* w_ih0 = (const float*)d_in[1];
    const float* w_hh0 = (const float*)d_in[2];
    const float* b_ih0 = (const float*)d_in[3];
    const float* b_hh0 = (const float*)d_in[4];
    const float* w_ih1 = (const float*)d_in[5];
    const float* w_hh1 = (const float*)d_in[6];
    const float* b_ih1 = (const float*)d_in[7];
    const float* b_hh1 = (const float*)d_in[8];
    const float* w_ih2 = (const float*)d_in[9];
    const float* w_hh2 = (const float*)d_in[10];
    const float* b_ih2 = (const float*)d_in[11];
    const float* b_hh2 = (const float*)d_in[12];
    const float* w_out = (const float*)d_in[13];
    const float* b_out = (const float*)d_in[14];
    float* out = (float*)d_out;

    const size_t TH = (size_t)T_STEPS * H_SZ;   // 512K floats = 2 MB
    float* PRE0 = (float*)d_ws;
    float* PRE1 = PRE0 + TH;
    float* PRE2 = PRE1 + TH;
    float* H0   = PRE2 + TH;
    float* H1   = H0 + TH;
    float* H2   = H1 + TH;
    int* flags  = (int*)(H2 + TH);              // 8 ints (ws ~12 MB + 32 B)

    hipMemsetAsync(flags, 0, 8 * sizeof(int), stream);  // ws is poisoned 0xAA

    pre_gemm_kernel<<<T_STEPS / 8, 512, 0, stream>>>(x, w_ih0, b_ih0, b_hh0, PRE0);

    pipeline_kernel<<<6, 512, 0, stream>>>(PRE0, w_hh0, w_hh1, w_hh2,
                                           w_ih1, w_ih2,
                                           b_ih1, b_hh1, b_ih2, b_hh2,
                                           w_out, b_out,
                                           H0, H1, H2, PRE1, PRE2,
                                           out, flags);
}

// Round 5
// 2889.061 us; speedup vs baseline: 1.0064x; 1.0064x over previous
//
#include <hip/hip_runtime.h>
#include <hip/hip_bf16.h>

// T=2048, B=64, IN=512, H=256, L=3, OUT=2.
// KEY INSIGHT 1: reference output = h[:, -1, :] = BATCH ELEMENT 63 only, and the
//   RNN recurrence is batch-diagonal -> compute a single-sequence 3-layer RNN (64x cut).
// KEY INSIGHT 2: layer l step t only needs layer l-1 outputs up to t -> run all
//   three scans CONCURRENTLY as a 6-block producer/consumer pipeline
//   (scan0 -> ih1 -> scan1 -> ih2 -> scan2 -> out), chunk-synchronized through
//   agent-scope flags.
// R4 bench: 2570us, VGPR_Count=84 -> float w[128] was SPILLED TO SCRATCH
//   (SROA runs pre-unroll, sees variable index; AMDGPU promote-alloca won't
//   vectorize 512B). 256KB/step scratch traffic = ~3000cy/step.
// R5 fix: 32 NAMED float4 registers via REP32 macro -> statically indexed at
//   all compiler stages, must allocate in VGPRs (~160, no spill till ~450).
// Critical-path floor: 2048 steps x 512 cy (65536 f32 MACs / 128 FMA-lanes/CU/cy).

#define T_STEPS 2048
#define B_SZ    64
#define IN_F    512
#define H_SZ    256
#define OUT_F   2
#define CHUNK   16
#define NCHUNK  (T_STEPS / CHUNK)

// ---- 32x macro engine: forces weight fragments into named VGPRs ------------
#define REP32(M) M(0) M(1) M(2) M(3) M(4) M(5) M(6) M(7) \
                 M(8) M(9) M(10) M(11) M(12) M(13) M(14) M(15) \
                 M(16) M(17) M(18) M(19) M(20) M(21) M(22) M(23) \
                 M(24) M(25) M(26) M(27) M(28) M(29) M(30) M(31)

#define W_DECL(n) const float4 wq##n = wrow[n];
#define W_FMA(n)  { float4 hv = hv4[n];                \
                    a0 = fmaf(wq##n.x, hv.x, a0);      \
                    a1 = fmaf(wq##n.y, hv.y, a1);      \
                    a2 = fmaf(wq##n.z, hv.z, a2);      \
                    a3 = fmaf(wq##n.w, hv.w, a3); }

__device__ __forceinline__ float fast_tanh(float x) {
    // tanh(x) = 1 - 2/(e^{2x}+1); v_exp-based, ~1e-6 rel err, saturates correctly.
    float e = __expf(2.f * x);
    return 1.f - 2.f / (e + 1.f);
}

// ---- cross-block chunk synchronization (agent scope, cross-XCD safe) --------
__device__ __forceinline__ void wait_ge(int* flag, int target) {
    if (threadIdx.x == 0) {
        while (__hip_atomic_load(flag, __ATOMIC_ACQUIRE, __HIP_MEMORY_SCOPE_AGENT) < target)
            __builtin_amdgcn_s_sleep(1);
    }
    __syncthreads();
}

__device__ __forceinline__ void post_flag(int* flag, int val) {
    __threadfence();   // each thread's global writes visible at agent scope
    __syncthreads();   // all threads fenced before the release store
    if (threadIdx.x == 0)
        __hip_atomic_store(flag, val, __ATOMIC_RELEASE, __HIP_MEMORY_SCOPE_AGENT);
}

// ---------------------------------------------------------------------------
// Recurrent scan stage: h_t = tanh(pre_t + W_hh h_{t-1}). 512 threads.
// Thread t: row j=t>>1, half p=t&1 holds W_hh[j][p*128..] in 32 NAMED float4
// VGPRs (wq0..wq31 -- R5 fix, no scratch). h double-buffered in LDS -> ONE
// barrier per step. Half-row partials combined via shfl_xor(1).
// pre chunk staged in LDS ps[][] -> per-step ps[r][j] is a broadcast LDS read.
// ---------------------------------------------------------------------------
__device__ void scan_stage(const float* __restrict__ pre, const float* __restrict__ Whh,
                           float* __restrict__ Hout, int* wait_f, int* post_f)
{
    __shared__ __align__(16) float h2[2][H_SZ];          // 2 KB
    __shared__ __align__(16) float ps[CHUNK][H_SZ];      // 16 KB
    const int tid = threadIdx.x;
    const int j = tid >> 1;
    const int p = tid & 1;

    const float4* wrow = (const float4*)(Whh + j * H_SZ + p * 128);
    REP32(W_DECL)                                        // wq0..wq31 in VGPRs

    if (tid < H_SZ) h2[0][tid] = 0.f;
    __syncthreads();

    int buf = 0;
    for (int c = 0; c < NCHUNK; ++c) {
        if (wait_f) wait_ge(wait_f, c + 1);

        // stage this chunk's 16x256 pre block into LDS, coalesced float4
        {
            const float4* src = (const float4*)(pre + (size_t)c * CHUNK * H_SZ);
            float4* dst = (float4*)&ps[0][0];
            dst[tid]       = src[tid];
            dst[tid + 512] = src[tid + 512];
        }
        __syncthreads();

        #pragma unroll 1
        for (int r = 0; r < CHUNK; ++r) {
            const float4* hv4 = (const float4*)(h2[buf] + p * 128);
            float a0 = 0.f, a1 = 0.f, a2 = 0.f, a3 = 0.f;
            REP32(W_FMA)
            float acc = (a0 + a1) + (a2 + a3);
            acc += __shfl_xor(acc, 1);               // combine half-row partials
            float hn = fast_tanh(ps[r][j] + acc);    // both lanes (no divergence)
            if (p == 0) {
                h2[buf ^ 1][j] = hn;                 // write OTHER buffer
                Hout[(size_t)(c * CHUNK + r) * H_SZ + j] = hn;
            }
            __syncthreads();                         // single barrier per step
            buf ^= 1;
        }
        if (post_f) post_flag(post_f, c + 1);
    }
}

// ---------------------------------------------------------------------------
// Streaming input-projection stage: PRE[t][j] = b1[j]+b2[j] + W_ih[j,:] . Hin[t,:]
// Same register/thread layout as scan; consumes H chunks, produces PRE chunks.
// ---------------------------------------------------------------------------
__device__ void ih_stage(const float* __restrict__ Hin, const float* __restrict__ Wih,
                         const float* __restrict__ b1, const float* __restrict__ b2,
                         float* __restrict__ PREout, int* wait_f, int* post_f)
{
    __shared__ __align__(16) float xs[CHUNK][H_SZ];   // 16 KB
    const int tid = threadIdx.x;
    const int j = tid >> 1;
    const int p = tid & 1;

    const float4* wrow = (const float4*)(Wih + j * H_SZ + p * 128);
    REP32(W_DECL)                                     // wq0..wq31 in VGPRs

    const float bb = b1[j] + b2[j];

    for (int c = 0; c < NCHUNK; ++c) {
        wait_ge(wait_f, c + 1);
        // stage the 16x256 h chunk into LDS, coalesced float4
        {
            const float4* src = (const float4*)(Hin + (size_t)c * CHUNK * H_SZ);
            float4* dst = (float4*)&xs[0][0];
            dst[tid]       = src[tid];
            dst[tid + 512] = src[tid + 512];
        }
        __syncthreads();

        #pragma unroll 1
        for (int r = 0; r < CHUNK; ++r) {
            const float4* hv4 = (const float4*)(xs[r] + p * 128);
            float a0 = 0.f, a1 = 0.f, a2 = 0.f, a3 = 0.f;
            REP32(W_FMA)
            float acc = (a0 + a1) + (a2 + a3);
            acc += __shfl_xor(acc, 1);
            if (p == 0)
                PREout[(size_t)(c * CHUNK + r) * H_SZ + j] = acc + bb;
        }
        post_flag(post_f, c + 1);   // fence+barrier also protects xs reuse
    }
}

// ---------------------------------------------------------------------------
// Output-projection stage: out[t][o] = b_out[o] + w_out[o,:] . H2[t,:].
// Wave w handles timesteps 2w, 2w+1 of each chunk (trivial work, pipeline shadow).
// ---------------------------------------------------------------------------
__device__ void out_stage(const float* __restrict__ Hs, const float* __restrict__ Wout,
                          const float* __restrict__ bout, float* __restrict__ out,
                          int* wait_f)
{
    const int tid = threadIdx.x;
    const int wv = tid >> 6;     // wave 0..7
    const int l  = tid & 63;

    const float w00 = Wout[l];
    const float w01 = Wout[l + 64];
    const float w02 = Wout[l + 128];
    const float w03 = Wout[l + 192];
    const float w10 = Wout[H_SZ + l];
    const float w11 = Wout[H_SZ + l + 64];
    const float w12 = Wout[H_SZ + l + 128];
    const float w13 = Wout[H_SZ + l + 192];
    const float b0 = bout[0], b1 = bout[1];

    for (int c = 0; c < NCHUNK; ++c) {
        wait_ge(wait_f, c + 1);
        #pragma unroll
        for (int s = 0; s < 2; ++s) {
            const int t = c * CHUNK + wv * 2 + s;
            const float* hrow = Hs + (size_t)t * H_SZ;
            float h0 = hrow[l], h1 = hrow[l + 64], h2 = hrow[l + 128], h3 = hrow[l + 192];
            float a0 = fmaf(h0, w00, fmaf(h1, w01, fmaf(h2, w02, h3 * w03)));
            float a1 = fmaf(h0, w10, fmaf(h1, w11, fmaf(h2, w12, h3 * w13)));
            #pragma unroll
            for (int sh = 32; sh; sh >>= 1) {
                a0 += __shfl_xor(a0, sh);
                a1 += __shfl_xor(a1, sh);
            }
            if (l == 0) {
                out[t * OUT_F + 0] = a0 + b0;
                out[t * OUT_F + 1] = a1 + b1;
            }
        }
    }
}

// ---------------------------------------------------------------------------
// 6-block pipeline (all co-resident: 6 blocks << 256 CUs).
// flags: 0=H0, 1=PRE1, 2=H1, 3=PRE2, 4=H2 chunk progress.
// ---------------------------------------------------------------------------
__global__ __launch_bounds__(512, 1)
void pipeline_kernel(const float* __restrict__ PRE0,
                     const float* __restrict__ w_hh0, const float* __restrict__ w_hh1,
                     const float* __restrict__ w_hh2,
                     const float* __restrict__ w_ih1, const float* __restrict__ w_ih2,
                     const float* __restrict__ b_ih1, const float* __restrict__ b_hh1,
                     const float* __restrict__ b_ih2, const float* __restrict__ b_hh2,
                     const float* __restrict__ w_out, const float* __restrict__ b_out,
                     float* __restrict__ H0, float* __restrict__ H1, float* __restrict__ H2,
                     float* __restrict__ PRE1, float* __restrict__ PRE2,
                     float* __restrict__ out, int* __restrict__ flags)
{
    switch (blockIdx.x) {
    case 0: scan_stage(PRE0, w_hh0, H0, nullptr,   flags + 0); break;
    case 1: ih_stage(H0, w_ih1, b_ih1, b_hh1, PRE1, flags + 0, flags + 1); break;
    case 2: scan_stage(PRE1, w_hh1, H1, flags + 1, flags + 2); break;
    case 3: ih_stage(H1, w_ih2, b_ih2, b_hh2, PRE2, flags + 2, flags + 3); break;
    case 4: scan_stage(PRE2, w_hh2, H2, flags + 3, flags + 4); break;
    case 5: out_stage(H2, w_out, b_out, out, flags + 4); break;
    }
}

// ---------------------------------------------------------------------------
// Layer-0 pre-GEMM (batch 63 only), fully parallel. 512 threads, 8 t per block,
// same half-row j/p layout as the scan stages. Off the critical path (~5us).
// ---------------------------------------------------------------------------
__global__ __launch_bounds__(512)
void pre_gemm_kernel(const float* __restrict__ in,
                     const float* __restrict__ W,
                     const float* __restrict__ b1, const float* __restrict__ b2,
                     float* __restrict__ pre)
{
    __shared__ __align__(16) float xs[8][IN_F];   // 16 KB
    const int tid = threadIdx.x;
    const int j = tid >> 1;
    const int p = tid & 1;
    const long t0 = (long)blockIdx.x * 8;

    // stage 8 input rows (batch 63) into LDS, coalesced float4 (128 f4/row)
    for (int idx = tid; idx < 8 * (IN_F / 4); idx += 512) {
        const int r = idx >> 7;
        const int q = idx & 127;
        const float4* srow = (const float4*)(in + (t0 + r) * ((long)B_SZ * IN_F)
                                                + (long)(B_SZ - 1) * IN_F);
        ((float4*)xs[r])[q] = srow[q];
    }
    __syncthreads();

    float acc[8] = {0.f, 0.f, 0.f, 0.f, 0.f, 0.f, 0.f, 0.f};
    const float4* wr = (const float4*)(W + (long)j * IN_F + p * (IN_F / 2));
    #pragma unroll 2
    for (int q = 0; q < IN_F / 8; ++q) {          // 64 float4 = half row (256 f)
        float4 wv = wr[q];
        #pragma unroll
        for (int r = 0; r < 8; ++r) {
            float4 xv = ((const float4*)(xs[r] + p * (IN_F / 2)))[q];
            acc[r] = fmaf(wv.x, xv.x, acc[r]);
            acc[r] = fmaf(wv.y, xv.y, acc[r]);
            acc[r] = fmaf(wv.z, xv.z, acc[r]);
            acc[r] = fmaf(wv.w, xv.w, acc[r]);
        }
    }
    const float bb = b1[j] + b2[j];
    #pragma unroll
    for (int r = 0; r < 8; ++r) {
        float v = acc[r] + __shfl_xor(acc[r], 1); // combine half-row partials
        if (p == 0)
            pre[(t0 + r) * H_SZ + j] = v + bb;
    }
}

// ---------------------------------------------------------------------------
extern "C" void kernel_launch(void* const* d_in, const int* in_sizes, int n_in,
                              void* d_out, int out_size, void* d_ws, size_t ws_size,
                              hipStream_t stream)
{
    const float* x     = (const float*)d_in[0];
    const float* w_ih0 = (const float*)d_in[1];
    const float* w_hh0 = (const float*)d_in[2];
    const float* b_ih0 = (const float*)d_in[3];
    const float* b_hh0 = (const float*)d_in[4];
    const float* w_ih1 = (const float*)d_in[5];
    const float* w_hh1 = (const float*)d_in[6];
    const float* b_ih1 = (const float*)d_in[7];
    const float* b_hh1 = (const float*)d_in[8];
    const float* w_ih2 = (const float*)d_in[9];
    const float* w_hh2 = (const float*)d_in[10];
    const float* b_ih2 = (const float*)d_in[11];
    const float* b_hh2 = (const float*)d_in[12];
    const float* w_out = (const float*)d_in[13];
    const float* b_out = (const float*)d_in[14];
    float* out = (float*)d_out;

    const size_t TH = (size_t)T_STEPS * H_SZ;   // 512K floats = 2 MB
    float* PRE0 = (float*)d_ws;
    float* PRE1 = PRE0 + TH;
    float* PRE2 = PRE1 + TH;
    float* H0   = PRE2 + TH;
    float* H1   = H0 + TH;
    float* H2   = H1 + TH;
    int* flags  = (int*)(H2 + TH);              // 8 ints (ws ~12 MB + 32 B)

    hipMemsetAsync(flags, 0, 8 * sizeof(int), stream);  // ws is poisoned 0xAA

    pre_gemm_kernel<<<T_STEPS / 8, 512, 0, stream>>>(x, w_ih0, b_ih0, b_hh0, PRE0);

    pipeline_kernel<<<6, 512, 0, stream>>>(PRE0, w_hh0, w_hh1, w_hh2,
                                           w_ih1, w_ih2,
                                           b_ih1, b_hh1, b_ih2, b_hh2,
                                           w_out, b_out,
                                           H0, H1, H2, PRE1, PRE2,
                                           out, flags);
}

// Round 8
// 2511.512 us; speedup vs baseline: 1.1576x; 1.1503x over previous
//
#include <hip/hip_runtime.h>
#include <hip/hip_bf16.h>

// T=2048, B=64, IN=512, H=256, L=3, OUT=2.
// KEY INSIGHT 1: reference output = h[:, -1, :] = BATCH ELEMENT 63 only; recurrence
//   is batch-diagonal -> single-sequence 3-layer RNN (64x cut).
// KEY INSIGHT 2: 6-block producer/consumer pipeline (scan0->ih1->scan1->ih2->scan2->out),
//   chunk-synchronized via agent-scope flags.
// R5 post-mortem: LDS READ THROUGHPUT bound, not spill. Old layout: every thread
//   re-read 512B of h per step = 256 ds_read_b128/step ~= 3000cy/step (m134: 12cy/b128).
// R6/R7/R8 (R6,R7 never ran - acquisition timeouts; resubmitted unchanged):
//   tile matvec 4 rows x 32 cols per thread -> 64 ds_read_b128/step (~770cy),
//   butterfly-reduce partials over 8 lanes (xor 1,2 = DPP; xor 4 = 1 ds-op/acc).
//   Gather rotated by (seg+i)&7 -> 8 distinct addrs cover all 32 banks,
//   conflict-free, 8-lane broadcast each. Weights reg-resident:
//   amdgpu_waves_per_eu(2,2) + asm pins.
// FMA floor: 512cy/step (65536 MACs / 128 lanes/cy/CU).

#define T_STEPS 2048
#define B_SZ    64
#define IN_F    512
#define H_SZ    256
#define OUT_F   2
#define CHUNK   16
#define NCHUNK  (T_STEPS / CHUNK)

typedef __attribute__((ext_vector_type(4))) float f32x4;

#define REP8(M) M(0) M(1) M(2) M(3) M(4) M(5) M(6) M(7)

__device__ __forceinline__ float fast_tanh(float x) {
    // tanh(x) = 1 - 2/(e^{2x}+1); v_exp-based, ~1e-6 rel err, saturates correctly.
    float e = __expf(2.f * x);
    return 1.f - 2.f / (e + 1.f);
}

// ---- cross-block chunk synchronization (agent scope, cross-XCD safe) --------
__device__ __forceinline__ void wait_ge(int* flag, int target) {
    if (threadIdx.x == 0) {
        while (__hip_atomic_load(flag, __ATOMIC_ACQUIRE, __HIP_MEMORY_SCOPE_AGENT) < target)
            __builtin_amdgcn_s_sleep(1);
    }
    __syncthreads();
}

__device__ __forceinline__ void post_flag(int* flag, int val) {
    __threadfence();   // each thread's global writes visible at agent scope
    __syncthreads();   // all threads fenced before the release store
    if (threadIdx.x == 0)
        __hip_atomic_store(flag, val, __ATOMIC_RELEASE, __HIP_MEMORY_SCOPE_AGENT);
}

// ---- shared tile machinery: 4 rows x 32 cols per thread ---------------------
// ro##i  : float offset of gather quad i within this thread's 32-col segment
// w{r}_i : weight quad, row r, rotated slot i (pairs with gather slot i)
#define RO_DECL(i) const int ro##i = (((seg + i) & 7) << 2);

#define W_DECL(i) \
    f32x4 w0_##i = *(const f32x4*)(wbase + 0 * H_SZ + ro##i); \
    f32x4 w1_##i = *(const f32x4*)(wbase + 1 * H_SZ + ro##i); \
    f32x4 w2_##i = *(const f32x4*)(wbase + 2 * H_SZ + ro##i); \
    f32x4 w3_##i = *(const f32x4*)(wbase + 3 * H_SZ + ro##i);

#define W_PIN8(a0,a1,a2,a3,a4,a5,a6,a7) \
    asm volatile("" : "+v"(a0), "+v"(a1), "+v"(a2), "+v"(a3), \
                      "+v"(a4), "+v"(a5), "+v"(a6), "+v"(a7));
#define W_PIN_ALL \
    W_PIN8(w0_0, w0_1, w0_2, w0_3, w0_4, w0_5, w0_6, w0_7) \
    W_PIN8(w1_0, w1_1, w1_2, w1_3, w1_4, w1_5, w1_6, w1_7) \
    W_PIN8(w2_0, w2_1, w2_2, w2_3, w2_4, w2_5, w2_6, w2_7) \
    W_PIN8(w3_0, w3_1, w3_2, w3_3, w3_4, w3_5, w3_6, w3_7)

#define TILE_FMA(i) { \
    const f32x4 hq = *(const f32x4*)(hb + ro##i); \
    a0 = fmaf(w0_##i.x, hq.x, fmaf(w0_##i.y, hq.y, fmaf(w0_##i.z, hq.z, fmaf(w0_##i.w, hq.w, a0)))); \
    a1 = fmaf(w1_##i.x, hq.x, fmaf(w1_##i.y, hq.y, fmaf(w1_##i.z, hq.z, fmaf(w1_##i.w, hq.w, a1)))); \
    a2 = fmaf(w2_##i.x, hq.x, fmaf(w2_##i.y, hq.y, fmaf(w2_##i.z, hq.z, fmaf(w2_##i.w, hq.w, a2)))); \
    a3 = fmaf(w3_##i.x, hq.x, fmaf(w3_##i.y, hq.y, fmaf(w3_##i.z, hq.z, fmaf(w3_##i.w, hq.w, a3)))); }

#define BFLY_REDUCE \
    a0 += __shfl_xor(a0, 1); a1 += __shfl_xor(a1, 1); a2 += __shfl_xor(a2, 1); a3 += __shfl_xor(a3, 1); \
    a0 += __shfl_xor(a0, 2); a1 += __shfl_xor(a1, 2); a2 += __shfl_xor(a2, 2); a3 += __shfl_xor(a3, 2); \
    a0 += __shfl_xor(a0, 4); a1 += __shfl_xor(a1, 4); a2 += __shfl_xor(a2, 4); a3 += __shfl_xor(a3, 4);

// ---------------------------------------------------------------------------
// Recurrent scan stage: h_t = tanh(pre_t + W_hh h_{t-1}). 512 threads.
// seg = tid&7 (cols [32seg,32seg+32)), rb = tid>>3 (rows [4rb,4rb+4)).
// Per step: 8 rotated ds_read_b128 (conflict-free, 8-lane broadcast each),
// 128 FMA, butterfly over 8 lanes, seg==0 lane finishes rows 4rb..4rb+3.
// h double-buffered in LDS -> ONE barrier per step.
// ---------------------------------------------------------------------------
__device__ void scan_stage(const float* __restrict__ pre, const float* __restrict__ Whh,
                           float* __restrict__ Hout, int* wait_f, int* post_f)
{
    __shared__ __align__(16) float h2[2][H_SZ];          // 2 KB
    __shared__ __align__(16) float ps[CHUNK][H_SZ];      // 16 KB
    const int tid = threadIdx.x;
    const int seg = tid & 7;
    const int rb  = tid >> 3;

    REP8(RO_DECL)
    const float* wbase = Whh + (size_t)(rb << 2) * H_SZ + (seg << 5);
    REP8(W_DECL)

    if (tid < H_SZ) h2[0][tid] = 0.f;
    __syncthreads();

    int buf = 0;
    for (int c = 0; c < NCHUNK; ++c) {
        if (wait_f) wait_ge(wait_f, c + 1);
        W_PIN_ALL

        // stage this chunk's 16x256 pre block into LDS (f32x4 coalesced)
        {
            const f32x4* src = (const f32x4*)(pre + (size_t)c * CHUNK * H_SZ);
            f32x4* dst = (f32x4*)&ps[0][0];
            dst[tid]       = src[tid];
            dst[tid + 512] = src[tid + 512];
        }
        __syncthreads();

        #pragma unroll 1
        for (int r = 0; r < CHUNK; ++r) {
            const float* hb = &h2[buf][seg << 5];
            float a0 = 0.f, a1 = 0.f, a2 = 0.f, a3 = 0.f;
            REP8(TILE_FMA)
            BFLY_REDUCE
            if (seg == 0) {
                const f32x4 pv = *(const f32x4*)&ps[r][rb << 2];
                f32x4 hn;
                hn.x = fast_tanh(a0 + pv.x);
                hn.y = fast_tanh(a1 + pv.y);
                hn.z = fast_tanh(a2 + pv.z);
                hn.w = fast_tanh(a3 + pv.w);
                *(f32x4*)&h2[buf ^ 1][rb << 2] = hn;
                *(f32x4*)(Hout + (size_t)(c * CHUNK + r) * H_SZ + (rb << 2)) = hn;
            }
            __syncthreads();                 // single barrier per step
            buf ^= 1;
        }
        if (post_f) post_flag(post_f, c + 1);
    }
}

// ---------------------------------------------------------------------------
// Streaming input-projection stage: PRE[t][j] = b1[j]+b2[j] + W_ih[j,:] . Hin[t,:]
// Same tile layout; the 16 matvecs of a chunk are INDEPENDENT -> no per-step
// barrier, deep ILP across steps.
// ---------------------------------------------------------------------------
__device__ void ih_stage(const float* __restrict__ Hin, const float* __restrict__ Wih,
                         const float* __restrict__ b1, const float* __restrict__ b2,
                         float* __restrict__ PREout, int* wait_f, int* post_f)
{
    __shared__ __align__(16) float xs[CHUNK][H_SZ];   // 16 KB
    const int tid = threadIdx.x;
    const int seg = tid & 7;
    const int rb  = tid >> 3;

    REP8(RO_DECL)
    const float* wbase = Wih + (size_t)(rb << 2) * H_SZ + (seg << 5);
    REP8(W_DECL)

    const f32x4 bb = *(const f32x4*)(b1 + (rb << 2)) + *(const f32x4*)(b2 + (rb << 2));

    for (int c = 0; c < NCHUNK; ++c) {
        wait_ge(wait_f, c + 1);
        W_PIN_ALL
        // stage the 16x256 h chunk into LDS (f32x4 coalesced)
        {
            const f32x4* src = (const f32x4*)(Hin + (size_t)c * CHUNK * H_SZ);
            f32x4* dst = (f32x4*)&xs[0][0];
            dst[tid]       = src[tid];
            dst[tid + 512] = src[tid + 512];
        }
        __syncthreads();

        #pragma unroll 1
        for (int r = 0; r < CHUNK; ++r) {
            const float* hb = &xs[r][seg << 5];
            float a0 = 0.f, a1 = 0.f, a2 = 0.f, a3 = 0.f;
            REP8(TILE_FMA)
            BFLY_REDUCE
            if (seg == 0) {
                f32x4 pv;
                pv.x = a0 + bb.x;
                pv.y = a1 + bb.y;
                pv.z = a2 + bb.z;
                pv.w = a3 + bb.w;
                *(f32x4*)(PREout + (size_t)(c * CHUNK + r) * H_SZ + (rb << 2)) = pv;
            }
        }
        post_flag(post_f, c + 1);   // fence+barrier also protects xs reuse
    }
}

// ---------------------------------------------------------------------------
// Output-projection stage: out[t][o] = b_out[o] + w_out[o,:] . H2[t,:].
// Wave w handles timesteps 2w, 2w+1 of each chunk (trivial, pipeline shadow).
// ---------------------------------------------------------------------------
__device__ void out_stage(const float* __restrict__ Hs, const float* __restrict__ Wout,
                          const float* __restrict__ bout, float* __restrict__ out,
                          int* wait_f)
{
    const int tid = threadIdx.x;
    const int wv = tid >> 6;     // wave 0..7
    const int l  = tid & 63;

    const float w00 = Wout[l];
    const float w01 = Wout[l + 64];
    const float w02 = Wout[l + 128];
    const float w03 = Wout[l + 192];
    const float w10 = Wout[H_SZ + l];
    const float w11 = Wout[H_SZ + l + 64];
    const float w12 = Wout[H_SZ + l + 128];
    const float w13 = Wout[H_SZ + l + 192];
    const float b0 = bout[0], b1 = bout[1];

    for (int c = 0; c < NCHUNK; ++c) {
        wait_ge(wait_f, c + 1);
        #pragma unroll
        for (int s = 0; s < 2; ++s) {
            const int t = c * CHUNK + wv * 2 + s;
            const float* hrow = Hs + (size_t)t * H_SZ;
            float h0 = hrow[l], h1 = hrow[l + 64], h2 = hrow[l + 128], h3 = hrow[l + 192];
            float a0 = fmaf(h0, w00, fmaf(h1, w01, fmaf(h2, w02, h3 * w03)));
            float a1 = fmaf(h0, w10, fmaf(h1, w11, fmaf(h2, w12, h3 * w13)));
            #pragma unroll
            for (int sh = 32; sh; sh >>= 1) {
                a0 += __shfl_xor(a0, sh);
                a1 += __shfl_xor(a1, sh);
            }
            if (l == 0) {
                out[t * OUT_F + 0] = a0 + b0;
                out[t * OUT_F + 1] = a1 + b1;
            }
        }
    }
}

// ---------------------------------------------------------------------------
// 6-block pipeline (all co-resident: 6 blocks << 256 CUs).
// flags: 0=H0, 1=PRE1, 2=H1, 3=PRE2, 4=H2 chunk progress.
// waves_per_eu(2,2): exactly 2 waves/SIMD -> VGPR budget 256, allocator must
// not chase occupancy -> weights stay register-resident.
// ---------------------------------------------------------------------------
__global__ __attribute__((amdgpu_waves_per_eu(2, 2))) __launch_bounds__(512)
void pipeline_kernel(const float* __restrict__ PRE0,
                     const float* __restrict__ w_hh0, const float* __restrict__ w_hh1,
                     const float* __restrict__ w_hh2,
                     const float* __restrict__ w_ih1, const float* __restrict__ w_ih2,
                     const float* __restrict__ b_ih1, const float* __restrict__ b_hh1,
                     const float* __restrict__ b_ih2, const float* __restrict__ b_hh2,
                     const float* __restrict__ w_out, const float* __restrict__ b_out,
                     float* __restrict__ H0, float* __restrict__ H1, float* __restrict__ H2,
                     float* __restrict__ PRE1, float* __restrict__ PRE2,
                     float* __restrict__ out, int* __restrict__ flags)
{
    switch (blockIdx.x) {
    case 0: scan_stage(PRE0, w_hh0, H0, nullptr,   flags + 0); break;
    case 1: ih_stage(H0, w_ih1, b_ih1, b_hh1, PRE1, flags + 0, flags + 1); break;
    case 2: scan_stage(PRE1, w_hh1, H1, flags + 1, flags + 2); break;
    case 3: ih_stage(H1, w_ih2, b_ih2, b_hh2, PRE2, flags + 2, flags + 3); break;
    case 4: scan_stage(PRE2, w_hh2, H2, flags + 3, flags + 4); break;
    case 5: out_stage(H2, w_out, b_out, out, flags + 4); break;
    }
}

// ---------------------------------------------------------------------------
// Layer-0 pre-GEMM (batch 63 only), fully parallel, off the critical path.
// ---------------------------------------------------------------------------
__global__ __launch_bounds__(512)
void pre_gemm_kernel(const float* __restrict__ in,
                     const float* __restrict__ W,
                     const float* __restrict__ b1, const float* __restrict__ b2,
                     float* __restrict__ pre)
{
    __shared__ __align__(16) float xs[8][IN_F];   // 16 KB
    const int tid = threadIdx.x;
    const int j = tid >> 1;
    const int p = tid & 1;
    const long t0 = (long)blockIdx.x * 8;

    for (int idx = tid; idx < 8 * (IN_F / 4); idx += 512) {
        const int r = idx >> 7;
        const int q = idx & 127;
        const float4* srow = (const float4*)(in + (t0 + r) * ((long)B_SZ * IN_F)
                                                + (long)(B_SZ - 1) * IN_F);
        ((float4*)xs[r])[q] = srow[q];
    }
    __syncthreads();

    float acc[8] = {0.f, 0.f, 0.f, 0.f, 0.f, 0.f, 0.f, 0.f};
    const float4* wr = (const float4*)(W + (long)j * IN_F + p * (IN_F / 2));
    #pragma unroll 2
    for (int q = 0; q < IN_F / 8; ++q) {
        float4 wv = wr[q];
        #pragma unroll
        for (int r = 0; r < 8; ++r) {
            float4 xv = ((const float4*)(xs[r] + p * (IN_F / 2)))[q];
            acc[r] = fmaf(wv.x, xv.x, acc[r]);
            acc[r] = fmaf(wv.y, xv.y, acc[r]);
            acc[r] = fmaf(wv.z, xv.z, acc[r]);
            acc[r] = fmaf(wv.w, xv.w, acc[r]);
        }
    }
    const float bb = b1[j] + b2[j];
    #pragma unroll
    for (int r = 0; r < 8; ++r) {
        float v = acc[r] + __shfl_xor(acc[r], 1);
        if (p == 0)
            pre[(t0 + r) * H_SZ + j] = v + bb;
    }
}

// ---------------------------------------------------------------------------
extern "C" void kernel_launch(void* const* d_in, const int* in_sizes, int n_in,
                              void* d_out, int out_size, void* d_ws, size_t ws_size,
                              hipStream_t stream)
{
    const float* x     = (const float*)d_in[0];
    const float* w_ih0 = (const float*)d_in[1];
    const float* w_hh0 = (const float*)d_in[2];
    const float* b_ih0 = (const float*)d_in[3];
    const float* b_hh0 = (const float*)d_in[4];
    const float* w_ih1 = (const float*)d_in[5];
    const float* w_hh1 = (const float*)d_in[6];
    const float* b_ih1 = (const float*)d_in[7];
    const float* b_hh1 = (const float*)d_in[8];
    const float* w_ih2 = (const float*)d_in[9];
    const float* w_hh2 = (const float*)d_in[10];
    const float* b_ih2 = (const float*)d_in[11];
    const float* b_hh2 = (const float*)d_in[12];
    const float* w_out = (const float*)d_in[13];
    const float* b_out = (const float*)d_in[14];
    float* out = (float*)d_out;

    const size_t TH = (size_t)T_STEPS * H_SZ;   // 512K floats = 2 MB
    float* PRE0 = (float*)d_ws;
    float* PRE1 = PRE0 + TH;
    float* PRE2 = PRE1 + TH;
    float* H0   = PRE2 + TH;
    float* H1   = H0 + TH;
    float* H2   = H1 + TH;
    int* flags  = (int*)(H2 + TH);              // 8 ints (ws ~12 MB + 32 B)

    hipMemsetAsync(flags, 0, 8 * sizeof(int), stream);  // ws is poisoned 0xAA

    pre_gemm_kernel<<<T_STEPS / 8, 512, 0, stream>>>(x, w_ih0, b_ih0, b_hh0, PRE0);

    pipeline_kernel<<<6, 512, 0, stream>>>(PRE0, w_hh0, w_hh1, w_hh2,
                                           w_ih1, w_ih2,
                                           b_ih1, b_hh1, b_ih2, b_hh2,
                                           w_out, b_out,
                                           H0, H1, H2, PRE1, PRE2,
                                           out, flags);
}